// Round 14
// baseline (197.796 us; speedup 1.0000x reference)
//
#include <hip/hip_runtime.h>

#define B_GRAPHS 64
#define MPG 32
#define TPG 8192
#define NM 2048
#define NT 524288
#define NL 65536
#define H 64
#define DT 18
#define DM 8

typedef __attribute__((ext_vector_type(8))) short bf8;
typedef __attribute__((ext_vector_type(4))) float f32x4;

__device__ __forceinline__ unsigned short f2bf(float f) {
    unsigned u = __builtin_bit_cast(unsigned, f);
    u += 0x7FFFu + ((u >> 16) & 1u);          // RNE
    return (unsigned short)(u >> 16);
}
__device__ __forceinline__ float bf2f(unsigned short h) {
    return __builtin_bit_cast(float, (unsigned)h << 16);
}

// ---------------------------------------------------------------------------
// K_A (round-11 task/machine/fold branches verbatim) + last-block k_graph tail.
//   blocks [0,512)   : tasks relu-sum partials — wave-autonomous MFMA path
//   blocks [512,576) : machine encoder + contrib (256 thr)
//   blocks [576,640) : weight folding            (64 active thr)
//   LAST block to finish (atomic counter) additionally runs the per-graph
//   aggregation for all 64 graphs (round-13 4-wave-parallel body, g-loop).
// ---------------------------------------------------------------------------
__global__ __launch_bounds__(256) void k_front(
    const float* __restrict__ xt,
    const float* __restrict__ t_ln_g, const float* __restrict__ t_ln_b,
    const float* __restrict__ t_w1, const float* __restrict__ t_b1,
    const float* __restrict__ xm,
    const float* __restrict__ m_ln_g, const float* __restrict__ m_ln_b,
    const float* __restrict__ m_w1, const float* __restrict__ m_b1,
    const float* __restrict__ m_w2, const float* __restrict__ m_b2,
    const float* __restrict__ lg_w1,
    const float* __restrict__ t_w2, const float* __restrict__ lg_w2,
    const float* __restrict__ o_w1, const float* __restrict__ t_b2,
    const float* __restrict__ lg_b1, const float* __restrict__ lg_b2,
    const float* __restrict__ o_b1,
    const float* __restrict__ a_w1, const float* __restrict__ a_b1,
    const float* __restrict__ a_w2, const float* __restrict__ a_b2,
    const int* __restrict__ mbatch,
    float* __restrict__ t_sum_partial,   // [512][64]
    float* __restrict__ t_cnt_partial,   // [512]
    float* __restrict__ mh,              // [2048][64]
    float* __restrict__ mh_contrib,      // [2049][64]
    float* __restrict__ W_comb, float* __restrict__ W2comb,
    float* __restrict__ biasA, float* __restrict__ bias2,
    float* __restrict__ aggr_contrib, int* __restrict__ cum,
    unsigned int* __restrict__ done_ctr)
{
    __shared__ float        s_stage[4608];   // 18 KB: 4 wave regions x 1152 dw
    __shared__ unsigned int s_pk[5248];      // 21 KB: 4 wave regions x 1312 dw
    __shared__ float s_part[4][64];
    __shared__ float s_h[4][64];
    __shared__ float s_m[4][64];
    __shared__ unsigned int s_is_last;

    int tid = threadIdx.x, lane = tid & 63, w = tid >> 6;
    int bid = blockIdx.x;

    if (bid < 512) {
        // ---------------- tasks part (wave-autonomous MFMA) ----------------
        int col = lane & 15, grp = lane >> 4;
        unsigned sbase = (unsigned)w * 1152u;
        unsigned pbase = (unsigned)w * 1312u;

        long rowbase = (long)bid * 1024 + (long)w * 256;
        const float4* src4 = (const float4*)(xt + rowbase * DT);

        float4 stg0, stg1, stg2, stg3, stg4;
        {
            const float4* p = src4;
            stg0 = p[lane]; stg1 = p[64 + lane];
            stg2 = p[128 + lane]; stg3 = p[192 + lane];
            if (lane < 32) stg4 = p[256 + lane];
        }

        bf8 bfrag[4];
        float b1c[4];
#pragma unroll
        for (int t = 0; t < 4; t++) {
#pragma unroll
            for (int j = 0; j < 8; j++) {
                int k = grp * 8 + j;
                float wv = (k < DT) ? t_w1[k * H + t * 16 + col] : 0.0f;
                bfrag[t][j] = (short)f2bf(wv);
            }
            b1c[t] = t_b1[t * 16 + col];
        }
        float lg[DT], lb[DT];
#pragma unroll
        for (int i = 0; i < DT; i++) { lg[i] = t_ln_g[i]; lb[i] = t_ln_b[i]; }

        float colsum[4] = {0.0f, 0.0f, 0.0f, 0.0f};

#pragma unroll 1
        for (int it = 0; it < 4; it++) {
            float4* sd = (float4*)(s_stage + sbase);
            sd[lane] = stg0; sd[64 + lane] = stg1;
            sd[128 + lane] = stg2; sd[192 + lane] = stg3;
            if (lane < 32) sd[256 + lane] = stg4;

            if (it < 3) {
                const float4* p = src4 + (it + 1) * 288;
                stg0 = p[lane]; stg1 = p[64 + lane];
                stg2 = p[128 + lane]; stg3 = p[192 + lane];
                if (lane < 32) stg4 = p[256 + lane];
            }

            asm volatile("s_waitcnt lgkmcnt(0)" ::: "memory");

            const float* srow = s_stage + sbase + lane * DT;
            float xv[DT];
#pragma unroll
            for (int q = 0; q < 9; q++) {
                float2 v = *(const float2*)(srow + 2 * q);
                xv[2 * q] = v.x; xv[2 * q + 1] = v.y;
            }
            float mu = 0.0f;
#pragma unroll
            for (int i = 0; i < DT; i++) mu += xv[i];
            mu *= (1.0f / DT);
            float var = 0.0f;
#pragma unroll
            for (int i = 0; i < DT; i++) { float d = xv[i] - mu; var += d * d; }
            var *= (1.0f / DT);
            float rs = rsqrtf(var + 1e-5f);
            unsigned int pk[16];
#pragma unroll
            for (int q = 0; q < 9; q++) {
                float a0 = (xv[2 * q]     - mu) * rs * lg[2 * q]     + lb[2 * q];
                float a1 = (xv[2 * q + 1] - mu) * rs * lg[2 * q + 1] + lb[2 * q + 1];
                pk[q] = (unsigned int)f2bf(a0) | ((unsigned int)f2bf(a1) << 16);
            }
#pragma unroll
            for (int q = 9; q < 16; q++) pk[q] = 0u;

            {
                unsigned off = pbase + (unsigned)lane * 20u + (((unsigned)lane >> 3) & 7) * 4u;
                uint4* dst = (uint4*)&s_pk[off];
                dst[0] = make_uint4(pk[0], pk[1], pk[2], pk[3]);
                dst[1] = make_uint4(pk[4], pk[5], pk[6], pk[7]);
                dst[2] = make_uint4(pk[8], pk[9], pk[10], pk[11]);
                dst[3] = make_uint4(pk[12], pk[13], pk[14], pk[15]);
            }
            asm volatile("s_waitcnt lgkmcnt(0)" ::: "memory");

#pragma unroll
            for (int s4i = 0; s4i < 4; s4i++) {
                unsigned row = (unsigned)(s4i * 16 + col);
                unsigned roff = pbase + row * 20u + ((row >> 3) & 7) * 4u
                              + (unsigned)grp * 4u;
                bf8 a = *(const bf8*)&s_pk[roff];
#pragma unroll
                for (int t = 0; t < 4; t++) {
                    f32x4 cini = {b1c[t], b1c[t], b1c[t], b1c[t]};
                    f32x4 d = __builtin_amdgcn_mfma_f32_16x16x32_bf16(a, bfrag[t], cini, 0, 0, 0);
                    colsum[t] += (fmaxf(d[0], 0.0f) + fmaxf(d[1], 0.0f))
                               + (fmaxf(d[2], 0.0f) + fmaxf(d[3], 0.0f));
                }
            }
        }

#pragma unroll
        for (int t = 0; t < 4; t++) {
            colsum[t] += __shfl_xor(colsum[t], 16);
            colsum[t] += __shfl_xor(colsum[t], 32);
        }
        if (lane < 16) {
#pragma unroll
            for (int t = 0; t < 4; t++) s_part[w][t * 16 + lane] = colsum[t];
        }
        __syncthreads();
        if (tid < 64) {
            float s = s_part[0][tid] + s_part[1][tid] + s_part[2][tid] + s_part[3][tid];
            t_sum_partial[bid * 64 + tid] = s;
        }
        if (tid == 0) t_cnt_partial[bid] = 1024.0f;

    } else if (bid < 576) {
        // ---------------- machines part ----------------
        int mbid = bid - 512;
        if (mbid == 0 && tid < 64) mh_contrib[(long)NM * H + tid] = 0.0f;

        float w1r[DM];
#pragma unroll
        for (int i = 0; i < DM; i++) w1r[i] = m_w1[i * H + lane];
        float w2r[H];
#pragma unroll
        for (int i = 0; i < H; i++) w2r[i] = m_w2[i * H + lane];
        float Cr[H];
#pragma unroll
        for (int i = 0; i < H; i++) Cr[i] = lg_w1[(2 * H + i) * H + lane];
        float b1 = m_b1[lane], b2 = m_b2[lane];
        float g0[DM], bb[DM];
#pragma unroll
        for (int i = 0; i < DM; i++) { g0[i] = m_ln_g[i]; bb[i] = m_ln_b[i]; }

        int W = mbid * 4 + w;
        for (int k = 0; k < 8; k++) {
            int m = W * 8 + k;
            float x[DM];
#pragma unroll
            for (int i = 0; i < DM; i++) x[i] = xm[m * DM + i];
            float mu = 0.0f;
#pragma unroll
            for (int i = 0; i < DM; i++) mu += x[i];
            mu *= (1.0f / DM);
            float var = 0.0f;
#pragma unroll
            for (int i = 0; i < DM; i++) { float d = x[i] - mu; var += d * d; }
            var *= (1.0f / DM);
            float rs = rsqrtf(var + 1e-5f);
            float h = b1;
#pragma unroll
            for (int i = 0; i < DM; i++) {
                float xn = (x[i] - mu) * rs * g0[i] + bb[i];
                h = fmaf(xn, w1r[i], h);
            }
            h = fmaxf(h, 0.0f);
            __syncthreads();
            s_h[w][lane] = h;
            __syncthreads();
            float o = b2;
#pragma unroll
            for (int i = 0; i < H; i++) o = fmaf(s_h[w][i], w2r[i], o);
            __syncthreads();
            s_m[w][lane] = o;
            __syncthreads();
            float c = 0.0f;
#pragma unroll
            for (int i = 0; i < H; i++) c = fmaf(s_m[w][i], Cr[i], c);
            mh[(long)m * H + lane] = o;
            mh_contrib[(long)m * H + lane] = c;
        }
    } else {
        // ---------------- fold part ----------------
        int i = bid - 576, j = tid;
        if (j < 64) {
            float a = 0.0f, b = 0.0f;
            for (int k = 0; k < H; k++) {
                a = fmaf(t_w2[i * H + k],  lg_w1[k * H + j], a);
                b = fmaf(lg_w2[i * H + k], o_w1[k * H + j], b);
            }
            W_comb[i * H + j] = a;
            W2comb[i * H + j] = b;
            if (i == 0) {
                float ba = lg_b1[j], b2v = o_b1[j];
                for (int k = 0; k < H; k++) {
                    ba  = fmaf(t_b2[k],  lg_w1[k * H + j], ba);
                    b2v = fmaf(lg_b2[k], o_w1[k * H + j], b2v);
                }
                biasA[j] = ba;
                bias2[j] = b2v;
            }
        }
    }

    // ---------------- last-block-done -> per-graph aggregation ----------------
    __syncthreads();                       // all block work issued
    if (tid == 0) {
        __threadfence();                   // device-scope release of our writes
        unsigned int prev = atomicAdd(done_ctr, 1u);
        s_is_last = (prev == (unsigned)(gridDim.x - 1)) ? 1u : 0u;
    }
    __syncthreads();
    if (s_is_last == 0u) return;
    __threadfence();                       // acquire all blocks' writes

    // round-13 4-wave k_graph body, looped over all 64 graphs.
    __shared__ float s_red[4][64];
    __shared__ float rs_[64], tm[64], mm[64], ah[64], ag[64];
    __shared__ float s_tcnt;
    __shared__ int   s_cnt[4][2];

#pragma unroll 1
    for (int g = 0; g < B_GRAPHS; g++) {
        {
            float s = 0.0f;
#pragma unroll
            for (int p = 0; p < 2; p++)
                s += t_sum_partial[(g * 8 + w * 2 + p) * 64 + lane];
            s_red[w][lane] = s;
        }
        {
            int clt = 0, ceq = 0;
#pragma unroll
            for (int k = 0; k < 8; k++) {
                int bt = mbatch[tid * 8 + k];
                clt += (bt < g) ? 1 : 0;
                ceq += (bt == g) ? 1 : 0;
            }
#pragma unroll
            for (int m = 1; m < 64; m <<= 1) {
                clt += __shfl_xor(clt, m);
                ceq += __shfl_xor(ceq, m);
            }
            if (lane == 0) { s_cnt[w][0] = clt; s_cnt[w][1] = ceq; }
        }
        if (tid == 0) {
            float c = 0.0f;
            for (int p = 0; p < 8; p++) c += t_cnt_partial[g * 8 + p];
            s_tcnt = c;
        }
        __syncthreads();
        if (tid < 64)
            rs_[tid] = s_red[0][tid] + s_red[1][tid] + s_red[2][tid] + s_red[3][tid];
        int mcnt = s_cnt[0][1] + s_cnt[1][1] + s_cnt[2][1] + s_cnt[3][1];
        if (tid == 0)
            cum[g] = s_cnt[0][0] + s_cnt[1][0] + s_cnt[2][0] + s_cnt[3][0];
        __syncthreads();                   // rs_ ready; s_red reuse below

        {
            float ms = 0.0f;
#pragma unroll
            for (int k = 0; k < 8; k++)
                ms += mh[(long)(g * MPG + w * 8 + k) * H + lane];
            s_red[w][lane] = ms;
        }
        __syncthreads();
        if (tid < 64)
            mm[tid] = (s_red[0][tid] + s_red[1][tid] + s_red[2][tid] + s_red[3][tid])
                    / fmaxf((float)mcnt, 1.0f);
        __syncthreads();

        {
            float d = 0.0f;
#pragma unroll
            for (int q = 0; q < 16; q++) {
                int i = w * 16 + q;
                d = fmaf(rs_[i], t_w2[i * H + lane], d);
            }
            s_red[w][lane] = d;
        }
        __syncthreads();
        if (tid < 64) {
            float tcnt = s_tcnt;
            float dot = s_red[0][tid] + s_red[1][tid] + s_red[2][tid] + s_red[3][tid];
            tm[tid] = (dot + tcnt * t_b2[tid]) / fmaxf(tcnt, 1.0f);
        }
        __syncthreads();

        {
            float h = 0.0f;
#pragma unroll
            for (int q = 0; q < 16; q++) {
                int i = w * 16 + q;
                h = fmaf(tm[i], a_w1[i * H + lane], h);
                h = fmaf(mm[i], a_w1[(H + i) * H + lane], h);
            }
            s_red[w][lane] = h;
        }
        __syncthreads();
        if (tid < 64) {
            float h = a_b1[tid] + s_red[0][tid] + s_red[1][tid] + s_red[2][tid] + s_red[3][tid];
            ah[tid] = fmaxf(h, 0.0f);
        }
        __syncthreads();

        {
            float o = 0.0f;
#pragma unroll
            for (int q = 0; q < 16; q++) {
                int i = w * 16 + q;
                o = fmaf(ah[i], a_w2[i * H + lane], o);
            }
            s_red[w][lane] = o;
        }
        __syncthreads();
        if (tid < 64)
            ag[tid] = a_b2[tid] + s_red[0][tid] + s_red[1][tid] + s_red[2][tid] + s_red[3][tid];
        __syncthreads();

        {
            float c = 0.0f;
#pragma unroll
            for (int q = 0; q < 16; q++) {
                int i = w * 16 + q;
                c = fmaf(ag[i], lg_w1[(H + i) * H + lane], c);
            }
            s_red[w][lane] = c;
        }
        __syncthreads();
        if (tid < 64)
            aggr_contrib[g * H + tid] = biasA[tid]
                + s_red[0][tid] + s_red[1][tid] + s_red[2][tid] + s_red[3][tid];
        __syncthreads();
    }
}

// ---------------------------------------------------------------------------
// K4 v6 (round-11 version, verbatim): split-bf16 MFMA label head.
// ---------------------------------------------------------------------------
__global__ __launch_bounds__(512) void k_labels_mma(
    const float* __restrict__ xt, const int* __restrict__ tbatch,
    const int* __restrict__ lidx,
    const float* __restrict__ t_ln_g, const float* __restrict__ t_ln_b,
    const float* __restrict__ t_w1, const float* __restrict__ t_b1,
    const float* __restrict__ W_comb, const float* __restrict__ W2comb,
    const float* __restrict__ bias2,
    const float* __restrict__ o_w2, const float* __restrict__ o_b2,
    const float* __restrict__ aggr_contrib, const float* __restrict__ mh_contrib,
    const int* __restrict__ cum,
    float* __restrict__ out)
{
    __shared__ float s_xn[DT * 128];
    __shared__ float s_w1[DT * H];
    __shared__ __align__(16) unsigned short s_Bhi[64 * 72];
    __shared__ __align__(16) unsigned short s_Blo[64 * 72];
    __shared__ __align__(16) unsigned short s_Ahi[128 * 72];
    __shared__ __align__(16) unsigned short s_Alo[128 * 72];
    __shared__ float s_b1v[H];
    __shared__ float s_lng[DT], s_lnb[DT];
    __shared__ int   s_gi[128], s_mi[128], s_t[128];

    int tid = threadIdx.x, lane = tid & 63, w = tid >> 6;
    int col = lane & 15, kg = lane >> 4;

    for (int i = tid; i < DT * H; i += 512) s_w1[i] = t_w1[i];
    if (tid < H) s_b1v[tid] = t_b1[tid];
    if (tid < DT) { s_lng[tid] = t_ln_g[tid]; s_lnb[tid] = t_ln_b[tid]; }
    if (tid < 128) {
        int t = lidx[blockIdx.x * 128 + tid];
        s_t[tid] = t;
        int g = tbatch[t];
        int assign = (int)xt[(long)t * DT];
        s_gi[tid] = g;
        s_mi[tid] = (assign < 0) ? NM : (assign + cum[g]);
    }
#pragma unroll
    for (int s = 0; s < 8; s++) {
        int idx = tid + s * 512;
        int i = idx >> 6, j = idx & 63;
        float v = W_comb[idx];
        unsigned short hi = f2bf(v);
        unsigned short lo = f2bf(v - bf2f(hi));
        s_Bhi[j * 72 + i] = hi;
        s_Blo[j * 72 + i] = lo;
    }
    __syncthreads();

    if (tid < 256) {
        int r = tid >> 1, hh = tid & 1;
        const float* src = xt + (long)s_t[r] * DT + hh * 9;
#pragma unroll
        for (int j = 0; j < 9; j++) s_xn[(hh * 9 + j) * 128 + r] = src[j];
    }
    __syncthreads();

    if (tid < 128) {
        float xv[DT];
#pragma unroll
        for (int i = 0; i < DT; i++) xv[i] = s_xn[i * 128 + tid];
        float mu = 0.0f;
#pragma unroll
        for (int i = 0; i < DT; i++) mu += xv[i];
        mu *= (1.0f / DT);
        float var = 0.0f;
#pragma unroll
        for (int i = 0; i < DT; i++) { float d = xv[i] - mu; var += d * d; }
        var *= (1.0f / DT);
        float rs = rsqrtf(var + 1e-5f);
#pragma unroll
        for (int i = 0; i < DT; i++)
            s_xn[i * 128 + tid] = (xv[i] - mu) * rs * s_lng[i] + s_lnb[i];
    }
    __syncthreads();

    int wb = w * 8;
    float acc0[8], acc1[8];
#pragma unroll
    for (int k = 0; k < 8; k++) { acc0[k] = s_b1v[wb + k]; acc1[k] = acc0[k]; }
    for (int i = 0; i < DT; i++) {
        float av0 = s_xn[i * 128 + lane];
        float av1 = s_xn[i * 128 + 64 + lane];
        const float4* wp = (const float4*)(s_w1 + i * H + wb);
        float4 wA = wp[0], wB = wp[1];
        acc0[0] = fmaf(av0, wA.x, acc0[0]); acc1[0] = fmaf(av1, wA.x, acc1[0]);
        acc0[1] = fmaf(av0, wA.y, acc0[1]); acc1[1] = fmaf(av1, wA.y, acc1[1]);
        acc0[2] = fmaf(av0, wA.z, acc0[2]); acc1[2] = fmaf(av1, wA.z, acc1[2]);
        acc0[3] = fmaf(av0, wA.w, acc0[3]); acc1[3] = fmaf(av1, wA.w, acc1[3]);
        acc0[4] = fmaf(av0, wB.x, acc0[4]); acc1[4] = fmaf(av1, wB.x, acc1[4]);
        acc0[5] = fmaf(av0, wB.y, acc0[5]); acc1[5] = fmaf(av1, wB.y, acc1[5]);
        acc0[6] = fmaf(av0, wB.z, acc0[6]); acc1[6] = fmaf(av1, wB.z, acc1[6]);
        acc0[7] = fmaf(av0, wB.w, acc0[7]); acc1[7] = fmaf(av1, wB.w, acc1[7]);
    }
    {
        unsigned int h0[4], l0[4], h1[4], l1[4];
#pragma unroll
        for (int q = 0; q < 4; q++) {
            float v0 = fmaxf(acc0[2 * q], 0.0f), v1 = fmaxf(acc0[2 * q + 1], 0.0f);
            unsigned short a = f2bf(v0), b = f2bf(v1);
            h0[q] = (unsigned)a | ((unsigned)b << 16);
            l0[q] = (unsigned)f2bf(v0 - bf2f(a)) | ((unsigned)f2bf(v1 - bf2f(b)) << 16);
            float u0 = fmaxf(acc1[2 * q], 0.0f), u1 = fmaxf(acc1[2 * q + 1], 0.0f);
            unsigned short c = f2bf(u0), d = f2bf(u1);
            h1[q] = (unsigned)c | ((unsigned)d << 16);
            l1[q] = (unsigned)f2bf(u0 - bf2f(c)) | ((unsigned)f2bf(u1 - bf2f(d)) << 16);
        }
        *(uint4*)&s_Ahi[lane * 72 + wb]        = make_uint4(h0[0], h0[1], h0[2], h0[3]);
        *(uint4*)&s_Alo[lane * 72 + wb]        = make_uint4(l0[0], l0[1], l0[2], l0[3]);
        *(uint4*)&s_Ahi[(64 + lane) * 72 + wb] = make_uint4(h1[0], h1[1], h1[2], h1[3]);
        *(uint4*)&s_Alo[(64 + lane) * 72 + wb] = make_uint4(l1[0], l1[1], l1[2], l1[3]);
    }
    __syncthreads();

    int labA = w * 16 + col;
    int labC = w * 16 + kg * 4;
    bf8 Ahi0 = *(const bf8*)&s_Ahi[labA * 72 + kg * 8];
    bf8 Ahi1 = *(const bf8*)&s_Ahi[labA * 72 + 32 + kg * 8];
    bf8 Alo0 = *(const bf8*)&s_Alo[labA * 72 + kg * 8];
    bf8 Alo1 = *(const bf8*)&s_Alo[labA * 72 + 32 + kg * 8];
    int gv[4], mv[4];
#pragma unroll
    for (int r = 0; r < 4; r++) { gv[r] = s_gi[labC + r]; mv[r] = s_mi[labC + r]; }

    f32x4 p1[4];
#pragma unroll
    for (int nt = 0; nt < 4; nt++) {
        int brow = nt * 16 + col;
        bf8 Bhi0 = *(const bf8*)&s_Bhi[brow * 72 + kg * 8];
        bf8 Bhi1 = *(const bf8*)&s_Bhi[brow * 72 + 32 + kg * 8];
        bf8 Blo0 = *(const bf8*)&s_Blo[brow * 72 + kg * 8];
        bf8 Blo1 = *(const bf8*)&s_Blo[brow * 72 + 32 + kg * 8];
        int dim = nt * 16 + col;
        f32x4 c;
#pragma unroll
        for (int r = 0; r < 4; r++)
            c[r] = aggr_contrib[gv[r] * H + dim] + mh_contrib[(long)mv[r] * H + dim];
        c = __builtin_amdgcn_mfma_f32_16x16x32_bf16(Alo0, Bhi0, c, 0, 0, 0);
        c = __builtin_amdgcn_mfma_f32_16x16x32_bf16(Alo1, Bhi1, c, 0, 0, 0);
        c = __builtin_amdgcn_mfma_f32_16x16x32_bf16(Ahi0, Blo0, c, 0, 0, 0);
        c = __builtin_amdgcn_mfma_f32_16x16x32_bf16(Ahi1, Blo1, c, 0, 0, 0);
        c = __builtin_amdgcn_mfma_f32_16x16x32_bf16(Ahi0, Bhi0, c, 0, 0, 0);
        c = __builtin_amdgcn_mfma_f32_16x16x32_bf16(Ahi1, Bhi1, c, 0, 0, 0);
        p1[nt] = c;
    }
    __syncthreads();

#pragma unroll
    for (int nt = 0; nt < 4; nt++) {
#pragma unroll
        for (int r = 0; r < 4; r++) {
            float v = fmaxf(p1[nt][r], 0.0f);
            unsigned short hi = f2bf(v);
            unsigned short lo = f2bf(v - bf2f(hi));
            int lab = labC + r;
            s_Ahi[lab * 72 + nt * 16 + col] = hi;
            s_Alo[lab * 72 + nt * 16 + col] = lo;
        }
    }
#pragma unroll
    for (int s = 0; s < 8; s++) {
        int idx = tid + s * 512;
        int i = idx >> 6, j = idx & 63;
        float v = W2comb[idx];
        unsigned short hi = f2bf(v);
        unsigned short lo = f2bf(v - bf2f(hi));
        s_Bhi[j * 72 + i] = hi;
        s_Blo[j * 72 + i] = lo;
    }
    __syncthreads();

    bf8 Hhi0 = *(const bf8*)&s_Ahi[labA * 72 + kg * 8];
    bf8 Hhi1 = *(const bf8*)&s_Ahi[labA * 72 + 32 + kg * 8];
    bf8 Hlo0 = *(const bf8*)&s_Alo[labA * 72 + kg * 8];
    bf8 Hlo1 = *(const bf8*)&s_Alo[labA * 72 + 32 + kg * 8];

    float sv[4] = {0.0f, 0.0f, 0.0f, 0.0f};
#pragma unroll
    for (int nt = 0; nt < 4; nt++) {
        int brow = nt * 16 + col;
        bf8 Bhi0 = *(const bf8*)&s_Bhi[brow * 72 + kg * 8];
        bf8 Bhi1 = *(const bf8*)&s_Bhi[brow * 72 + 32 + kg * 8];
        bf8 Blo0 = *(const bf8*)&s_Blo[brow * 72 + kg * 8];
        bf8 Blo1 = *(const bf8*)&s_Blo[brow * 72 + 32 + kg * 8];
        int dim = nt * 16 + col;
        float bz = bias2[dim];
        f32x4 c = {bz, bz, bz, bz};
        c = __builtin_amdgcn_mfma_f32_16x16x32_bf16(Hlo0, Bhi0, c, 0, 0, 0);
        c = __builtin_amdgcn_mfma_f32_16x16x32_bf16(Hlo1, Bhi1, c, 0, 0, 0);
        c = __builtin_amdgcn_mfma_f32_16x16x32_bf16(Hhi0, Blo0, c, 0, 0, 0);
        c = __builtin_amdgcn_mfma_f32_16x16x32_bf16(Hhi1, Blo1, c, 0, 0, 0);
        c = __builtin_amdgcn_mfma_f32_16x16x32_bf16(Hhi0, Bhi0, c, 0, 0, 0);
        c = __builtin_amdgcn_mfma_f32_16x16x32_bf16(Hhi1, Bhi1, c, 0, 0, 0);
        float ow = o_w2[dim];
#pragma unroll
        for (int r = 0; r < 4; r++)
            sv[r] = fmaf(fmaxf(c[r], 0.0f), ow, sv[r]);
    }
#pragma unroll
    for (int r = 0; r < 4; r++) {
        sv[r] += __shfl_xor(sv[r], 1);
        sv[r] += __shfl_xor(sv[r], 2);
        sv[r] += __shfl_xor(sv[r], 4);
        sv[r] += __shfl_xor(sv[r], 8);
    }
    if (col == 0) {
        float ob = o_b2[0];
#pragma unroll
        for (int r = 0; r < 4; r++)
            out[blockIdx.x * 128 + labC + r] = ob + sv[r];
    }
}

// ---------------------------------------------------------------------------
extern "C" void kernel_launch(void* const* d_in, const int* in_sizes, int n_in,
                              void* d_out, int out_size, void* d_ws, size_t ws_size,
                              hipStream_t stream)
{
    (void)n_in; (void)out_size; (void)ws_size;
    const float* x_tasks         = (const float*)d_in[0];
    const float* x_machines      = (const float*)d_in[1];
    const int*   x_tasks_batch   = (const int*)d_in[2];
    const int*   x_machines_batch= (const int*)d_in[3];
    const int*   task_label_idx  = (const int*)d_in[4];
    const float* t_ln_g = (const float*)d_in[5];
    const float* t_ln_b = (const float*)d_in[6];
    const float *m_ln_g, *m_ln_b, *t_w1, *t_b1, *t_w2, *t_b2;
    if (in_sizes[7] == DM) {
        m_ln_g = (const float*)d_in[7];  m_ln_b = (const float*)d_in[8];
        t_w1   = (const float*)d_in[9];  t_b1   = (const float*)d_in[10];
        t_w2   = (const float*)d_in[11]; t_b2   = (const float*)d_in[12];
    } else {
        t_w1   = (const float*)d_in[7];  t_b1   = (const float*)d_in[8];
        t_w2   = (const float*)d_in[9];  t_b2   = (const float*)d_in[10];
        m_ln_g = (const float*)d_in[11]; m_ln_b = (const float*)d_in[12];
    }
    const float* m_w1 = (const float*)d_in[13]; const float* m_b1 = (const float*)d_in[14];
    const float* m_w2 = (const float*)d_in[15]; const float* m_b2 = (const float*)d_in[16];
    const float* a_w1 = (const float*)d_in[17]; const float* a_b1 = (const float*)d_in[18];
    const float* a_w2 = (const float*)d_in[19]; const float* a_b2 = (const float*)d_in[20];
    const float* lg_w1= (const float*)d_in[21]; const float* lg_b1= (const float*)d_in[22];
    const float* lg_w2= (const float*)d_in[23]; const float* lg_b2= (const float*)d_in[24];
    const float* o_w1 = (const float*)d_in[25]; const float* o_b1 = (const float*)d_in[26];
    const float* o_w2 = (const float*)d_in[27]; const float* o_b2 = (const float*)d_in[28];

    float* ws = (float*)d_ws;
    float* mh_contrib    = ws;                  // 2049*64 = 131136
    float* mh_arr        = ws + 131136;         // 2048*64 = 131072
    float* t_sum_partial = ws + 262208;         // 512*64  = 32768
    float* t_cnt_partial = ws + 294976;         // 512
    float* W_comb        = ws + 295488;         // 4096
    float* W2comb        = ws + 299584;         // 4096
    float* biasA         = ws + 303680;         // 64
    float* bias2         = ws + 303744;         // 64
    float* aggr_contrib  = ws + 303808;         // 4096
    int*   cum           = (int*)(ws + 307904); // 64
    unsigned int* done_ctr = (unsigned int*)(ws + 307968);

    hipMemsetAsync(done_ctr, 0, sizeof(unsigned int), stream);

    k_front<<<640, 256, 0, stream>>>(x_tasks, t_ln_g, t_ln_b, t_w1, t_b1,
                                     x_machines, m_ln_g, m_ln_b, m_w1, m_b1, m_w2, m_b2,
                                     lg_w1, t_w2, lg_w2, o_w1, t_b2, lg_b1, lg_b2, o_b1,
                                     a_w1, a_b1, a_w2, a_b2, x_machines_batch,
                                     t_sum_partial, t_cnt_partial, mh_arr, mh_contrib,
                                     W_comb, W2comb, biasA, bias2,
                                     aggr_contrib, cum, done_ctr);
    k_labels_mma<<<512, 512, 0, stream>>>(x_tasks, x_tasks_batch, task_label_idx,
                                          t_ln_g, t_ln_b, t_w1, t_b1, W_comb, W2comb, bias2,
                                          o_w2, o_b2, aggr_contrib, mh_contrib, cum,
                                          (float*)d_out);
}

// Round 15
// 43.241 us; speedup vs baseline: 4.5742x; 4.5742x over previous
//
#include <hip/hip_runtime.h>

#define B_GRAPHS 64
#define MPG 32
#define TPG 8192
#define NM 2048
#define NT 524288
#define NL 65536
#define H 64
#define DT 18
#define DM 8

typedef __attribute__((ext_vector_type(8))) short bf8;
typedef __attribute__((ext_vector_type(4))) float f32x4;

__device__ __forceinline__ unsigned short f2bf(float f) {
    unsigned u = __builtin_bit_cast(unsigned, f);
    u += 0x7FFFu + ((u >> 16) & 1u);          // RNE
    return (unsigned short)(u >> 16);
}
__device__ __forceinline__ float bf2f(unsigned short h) {
    return __builtin_bit_cast(float, (unsigned)h << 16);
}

// ---------------------------------------------------------------------------
// K_A: merged independent work (round-11 best configuration, verbatim).
//   blocks [0,512)   : tasks relu-sum partials — wave-autonomous MFMA path
//   blocks [512,576) : machine encoder + contrib (256 thr)
//   blocks [576,640) : weight folding            (64 active thr)
// ---------------------------------------------------------------------------
__global__ __launch_bounds__(256) void k_front(
    const float* __restrict__ xt,
    const float* __restrict__ t_ln_g, const float* __restrict__ t_ln_b,
    const float* __restrict__ t_w1, const float* __restrict__ t_b1,
    const float* __restrict__ xm,
    const float* __restrict__ m_ln_g, const float* __restrict__ m_ln_b,
    const float* __restrict__ m_w1, const float* __restrict__ m_b1,
    const float* __restrict__ m_w2, const float* __restrict__ m_b2,
    const float* __restrict__ lg_w1,
    const float* __restrict__ t_w2, const float* __restrict__ lg_w2,
    const float* __restrict__ o_w1, const float* __restrict__ t_b2,
    const float* __restrict__ lg_b1, const float* __restrict__ lg_b2,
    const float* __restrict__ o_b1,
    float* __restrict__ t_sum_partial,   // [512][64]
    float* __restrict__ t_cnt_partial,   // [512]
    float* __restrict__ mh,              // [2048][64]
    float* __restrict__ mh_contrib,      // [2049][64]
    float* __restrict__ W_comb, float* __restrict__ W2comb,
    float* __restrict__ biasA, float* __restrict__ bias2)
{
    __shared__ float        s_stage[4608];   // 18 KB: 4 wave regions x 1152 dw
    __shared__ unsigned int s_pk[5248];      // 21 KB: 4 wave regions x 1312 dw
    __shared__ float s_part[4][64];
    __shared__ float s_h[4][64];
    __shared__ float s_m[4][64];

    int tid = threadIdx.x, lane = tid & 63, w = tid >> 6;
    int bid = blockIdx.x;

    if (bid < 512) {
        int col = lane & 15, grp = lane >> 4;
        unsigned sbase = (unsigned)w * 1152u;
        unsigned pbase = (unsigned)w * 1312u;

        long rowbase = (long)bid * 1024 + (long)w * 256;
        const float4* src4 = (const float4*)(xt + rowbase * DT);

        float4 stg0, stg1, stg2, stg3, stg4;
        {
            const float4* p = src4;
            stg0 = p[lane]; stg1 = p[64 + lane];
            stg2 = p[128 + lane]; stg3 = p[192 + lane];
            if (lane < 32) stg4 = p[256 + lane];
        }

        bf8 bfrag[4];
        float b1c[4];
#pragma unroll
        for (int t = 0; t < 4; t++) {
#pragma unroll
            for (int j = 0; j < 8; j++) {
                int k = grp * 8 + j;
                float wv = (k < DT) ? t_w1[k * H + t * 16 + col] : 0.0f;
                bfrag[t][j] = (short)f2bf(wv);
            }
            b1c[t] = t_b1[t * 16 + col];
        }
        float lg[DT], lb[DT];
#pragma unroll
        for (int i = 0; i < DT; i++) { lg[i] = t_ln_g[i]; lb[i] = t_ln_b[i]; }

        float colsum[4] = {0.0f, 0.0f, 0.0f, 0.0f};

#pragma unroll 1
        for (int it = 0; it < 4; it++) {
            float4* sd = (float4*)(s_stage + sbase);
            sd[lane] = stg0; sd[64 + lane] = stg1;
            sd[128 + lane] = stg2; sd[192 + lane] = stg3;
            if (lane < 32) sd[256 + lane] = stg4;

            if (it < 3) {
                const float4* p = src4 + (it + 1) * 288;
                stg0 = p[lane]; stg1 = p[64 + lane];
                stg2 = p[128 + lane]; stg3 = p[192 + lane];
                if (lane < 32) stg4 = p[256 + lane];
            }

            asm volatile("s_waitcnt lgkmcnt(0)" ::: "memory");

            const float* srow = s_stage + sbase + lane * DT;
            float xv[DT];
#pragma unroll
            for (int q = 0; q < 9; q++) {
                float2 v = *(const float2*)(srow + 2 * q);
                xv[2 * q] = v.x; xv[2 * q + 1] = v.y;
            }
            float mu = 0.0f;
#pragma unroll
            for (int i = 0; i < DT; i++) mu += xv[i];
            mu *= (1.0f / DT);
            float var = 0.0f;
#pragma unroll
            for (int i = 0; i < DT; i++) { float d = xv[i] - mu; var += d * d; }
            var *= (1.0f / DT);
            float rs = rsqrtf(var + 1e-5f);
            unsigned int pk[16];
#pragma unroll
            for (int q = 0; q < 9; q++) {
                float a0 = (xv[2 * q]     - mu) * rs * lg[2 * q]     + lb[2 * q];
                float a1 = (xv[2 * q + 1] - mu) * rs * lg[2 * q + 1] + lb[2 * q + 1];
                pk[q] = (unsigned int)f2bf(a0) | ((unsigned int)f2bf(a1) << 16);
            }
#pragma unroll
            for (int q = 9; q < 16; q++) pk[q] = 0u;

            {
                unsigned off = pbase + (unsigned)lane * 20u + (((unsigned)lane >> 3) & 7) * 4u;
                uint4* dst = (uint4*)&s_pk[off];
                dst[0] = make_uint4(pk[0], pk[1], pk[2], pk[3]);
                dst[1] = make_uint4(pk[4], pk[5], pk[6], pk[7]);
                dst[2] = make_uint4(pk[8], pk[9], pk[10], pk[11]);
                dst[3] = make_uint4(pk[12], pk[13], pk[14], pk[15]);
            }
            asm volatile("s_waitcnt lgkmcnt(0)" ::: "memory");

#pragma unroll
            for (int s4i = 0; s4i < 4; s4i++) {
                unsigned row = (unsigned)(s4i * 16 + col);
                unsigned roff = pbase + row * 20u + ((row >> 3) & 7) * 4u
                              + (unsigned)grp * 4u;
                bf8 a = *(const bf8*)&s_pk[roff];
#pragma unroll
                for (int t = 0; t < 4; t++) {
                    f32x4 cini = {b1c[t], b1c[t], b1c[t], b1c[t]};
                    f32x4 d = __builtin_amdgcn_mfma_f32_16x16x32_bf16(a, bfrag[t], cini, 0, 0, 0);
                    colsum[t] += (fmaxf(d[0], 0.0f) + fmaxf(d[1], 0.0f))
                               + (fmaxf(d[2], 0.0f) + fmaxf(d[3], 0.0f));
                }
            }
        }

#pragma unroll
        for (int t = 0; t < 4; t++) {
            colsum[t] += __shfl_xor(colsum[t], 16);
            colsum[t] += __shfl_xor(colsum[t], 32);
        }
        if (lane < 16) {
#pragma unroll
            for (int t = 0; t < 4; t++) s_part[w][t * 16 + lane] = colsum[t];
        }
        __syncthreads();
        if (tid < 64) {
            float s = s_part[0][tid] + s_part[1][tid] + s_part[2][tid] + s_part[3][tid];
            t_sum_partial[bid * 64 + tid] = s;
        }
        if (tid == 0) t_cnt_partial[bid] = 1024.0f;

    } else if (bid < 576) {
        int mbid = bid - 512;
        if (mbid == 0 && tid < 64) mh_contrib[(long)NM * H + tid] = 0.0f;

        float w1r[DM];
#pragma unroll
        for (int i = 0; i < DM; i++) w1r[i] = m_w1[i * H + lane];
        float w2r[H];
#pragma unroll
        for (int i = 0; i < H; i++) w2r[i] = m_w2[i * H + lane];
        float Cr[H];
#pragma unroll
        for (int i = 0; i < H; i++) Cr[i] = lg_w1[(2 * H + i) * H + lane];
        float b1 = m_b1[lane], b2 = m_b2[lane];
        float g0[DM], bb[DM];
#pragma unroll
        for (int i = 0; i < DM; i++) { g0[i] = m_ln_g[i]; bb[i] = m_ln_b[i]; }

        int W = mbid * 4 + w;
        for (int k = 0; k < 8; k++) {
            int m = W * 8 + k;
            float x[DM];
#pragma unroll
            for (int i = 0; i < DM; i++) x[i] = xm[m * DM + i];
            float mu = 0.0f;
#pragma unroll
            for (int i = 0; i < DM; i++) mu += x[i];
            mu *= (1.0f / DM);
            float var = 0.0f;
#pragma unroll
            for (int i = 0; i < DM; i++) { float d = x[i] - mu; var += d * d; }
            var *= (1.0f / DM);
            float rs = rsqrtf(var + 1e-5f);
            float h = b1;
#pragma unroll
            for (int i = 0; i < DM; i++) {
                float xn = (x[i] - mu) * rs * g0[i] + bb[i];
                h = fmaf(xn, w1r[i], h);
            }
            h = fmaxf(h, 0.0f);
            __syncthreads();
            s_h[w][lane] = h;
            __syncthreads();
            float o = b2;
#pragma unroll
            for (int i = 0; i < H; i++) o = fmaf(s_h[w][i], w2r[i], o);
            __syncthreads();
            s_m[w][lane] = o;
            __syncthreads();
            float c = 0.0f;
#pragma unroll
            for (int i = 0; i < H; i++) c = fmaf(s_m[w][i], Cr[i], c);
            mh[(long)m * H + lane] = o;
            mh_contrib[(long)m * H + lane] = c;
        }
    } else {
        int i = bid - 576, j = tid;
        if (j < 64) {
            float a = 0.0f, b = 0.0f;
            for (int k = 0; k < H; k++) {
                a = fmaf(t_w2[i * H + k],  lg_w1[k * H + j], a);
                b = fmaf(lg_w2[i * H + k], o_w1[k * H + j], b);
            }
            W_comb[i * H + j] = a;
            W2comb[i * H + j] = b;
            if (i == 0) {
                float ba = lg_b1[j], b2v = o_b1[j];
                for (int k = 0; k < H; k++) {
                    ba  = fmaf(t_b2[k],  lg_w1[k * H + j], ba);
                    b2v = fmaf(lg_b2[k], o_w1[k * H + j], b2v);
                }
                biasA[j] = ba;
                bias2[j] = b2v;
            }
        }
    }
}

// ---------------------------------------------------------------------------
// K3: per-graph aggregation (round-11 version, verbatim).
// ---------------------------------------------------------------------------
__global__ __launch_bounds__(64) void k_graph(
    const float* __restrict__ t_sum_partial, const float* __restrict__ t_cnt_partial,
    const float* __restrict__ mh, const int* __restrict__ mbatch,
    const float* __restrict__ t_w2, const float* __restrict__ t_b2,
    const float* __restrict__ a_w1, const float* __restrict__ a_b1,
    const float* __restrict__ a_w2, const float* __restrict__ a_b2,
    const float* __restrict__ lg_w1, const float* __restrict__ biasA,
    float* __restrict__ aggr_contrib, int* __restrict__ cum)
{
    int g = blockIdx.x, j = threadIdx.x;
    __shared__ float rs_[64], tm[64], mm[64], ah[64], ag[64];
    __shared__ float s_tcnt;
    __shared__ int s_lt[64], s_eq[64];

    float s = 0.0f;
    for (int p = 0; p < 8; p++) s += t_sum_partial[(g * 8 + p) * 64 + j];
    rs_[j] = s;
    if (j == 0) {
        float c = 0.0f;
        for (int p = 0; p < 8; p++) c += t_cnt_partial[g * 8 + p];
        s_tcnt = c;
    }
    int clt = 0, ceq = 0;
    for (int k = 0; k < 32; k++) {
        int bt = mbatch[j * 32 + k];
        clt += (bt < g) ? 1 : 0;
        ceq += (bt == g) ? 1 : 0;
    }
    s_lt[j] = clt; s_eq[j] = ceq;
    float msum = 0.0f;
    for (int k = 0; k < MPG; k++) msum += mh[(long)(g * MPG + k) * H + j];
    __syncthreads();

    int cum_g = 0, mcnt = 0;
    for (int k = 0; k < 64; k++) { cum_g += s_lt[k]; mcnt += s_eq[k]; }
    if (j == 0) cum[g] = cum_g;

    float tcnt = s_tcnt;
    float dot = 0.0f;
    for (int i = 0; i < H; i++) dot = fmaf(rs_[i], t_w2[i * H + j], dot);
    tm[j] = (dot + tcnt * t_b2[j]) / fmaxf(tcnt, 1.0f);
    mm[j] = msum / fmaxf((float)mcnt, 1.0f);
    __syncthreads();

    float h = a_b1[j];
    for (int i = 0; i < H; i++) h = fmaf(tm[i], a_w1[i * H + j], h);
    for (int i = 0; i < H; i++) h = fmaf(mm[i], a_w1[(H + i) * H + j], h);
    ah[j] = fmaxf(h, 0.0f);
    __syncthreads();

    float o = a_b2[j];
    for (int i = 0; i < H; i++) o = fmaf(ah[i], a_w2[i * H + j], o);
    ag[j] = o;
    __syncthreads();

    float c = biasA[j];
    for (int i = 0; i < H; i++) c = fmaf(ag[i], lg_w1[(H + i) * H + j], c);
    aggr_contrib[g * H + j] = c;
}

// ---------------------------------------------------------------------------
// K4 v6 (round-11 version, verbatim): split-bf16 MFMA label head.
// ---------------------------------------------------------------------------
__global__ __launch_bounds__(512) void k_labels_mma(
    const float* __restrict__ xt, const int* __restrict__ tbatch,
    const int* __restrict__ lidx,
    const float* __restrict__ t_ln_g, const float* __restrict__ t_ln_b,
    const float* __restrict__ t_w1, const float* __restrict__ t_b1,
    const float* __restrict__ W_comb, const float* __restrict__ W2comb,
    const float* __restrict__ bias2,
    const float* __restrict__ o_w2, const float* __restrict__ o_b2,
    const float* __restrict__ aggr_contrib, const float* __restrict__ mh_contrib,
    const int* __restrict__ cum,
    float* __restrict__ out)
{
    __shared__ float s_xn[DT * 128];
    __shared__ float s_w1[DT * H];
    __shared__ __align__(16) unsigned short s_Bhi[64 * 72];
    __shared__ __align__(16) unsigned short s_Blo[64 * 72];
    __shared__ __align__(16) unsigned short s_Ahi[128 * 72];
    __shared__ __align__(16) unsigned short s_Alo[128 * 72];
    __shared__ float s_b1v[H];
    __shared__ float s_lng[DT], s_lnb[DT];
    __shared__ int   s_gi[128], s_mi[128], s_t[128];

    int tid = threadIdx.x, lane = tid & 63, w = tid >> 6;
    int col = lane & 15, kg = lane >> 4;

    for (int i = tid; i < DT * H; i += 512) s_w1[i] = t_w1[i];
    if (tid < H) s_b1v[tid] = t_b1[tid];
    if (tid < DT) { s_lng[tid] = t_ln_g[tid]; s_lnb[tid] = t_ln_b[tid]; }
    if (tid < 128) {
        int t = lidx[blockIdx.x * 128 + tid];
        s_t[tid] = t;
        int g = tbatch[t];
        int assign = (int)xt[(long)t * DT];
        s_gi[tid] = g;
        s_mi[tid] = (assign < 0) ? NM : (assign + cum[g]);
    }
#pragma unroll
    for (int s = 0; s < 8; s++) {
        int idx = tid + s * 512;
        int i = idx >> 6, j = idx & 63;
        float v = W_comb[idx];
        unsigned short hi = f2bf(v);
        unsigned short lo = f2bf(v - bf2f(hi));
        s_Bhi[j * 72 + i] = hi;
        s_Blo[j * 72 + i] = lo;
    }
    __syncthreads();

    if (tid < 256) {
        int r = tid >> 1, hh = tid & 1;
        const float* src = xt + (long)s_t[r] * DT + hh * 9;
#pragma unroll
        for (int j = 0; j < 9; j++) s_xn[(hh * 9 + j) * 128 + r] = src[j];
    }
    __syncthreads();

    if (tid < 128) {
        float xv[DT];
#pragma unroll
        for (int i = 0; i < DT; i++) xv[i] = s_xn[i * 128 + tid];
        float mu = 0.0f;
#pragma unroll
        for (int i = 0; i < DT; i++) mu += xv[i];
        mu *= (1.0f / DT);
        float var = 0.0f;
#pragma unroll
        for (int i = 0; i < DT; i++) { float d = xv[i] - mu; var += d * d; }
        var *= (1.0f / DT);
        float rs = rsqrtf(var + 1e-5f);
#pragma unroll
        for (int i = 0; i < DT; i++)
            s_xn[i * 128 + tid] = (xv[i] - mu) * rs * s_lng[i] + s_lnb[i];
    }
    __syncthreads();

    int wb = w * 8;
    float acc0[8], acc1[8];
#pragma unroll
    for (int k = 0; k < 8; k++) { acc0[k] = s_b1v[wb + k]; acc1[k] = acc0[k]; }
    for (int i = 0; i < DT; i++) {
        float av0 = s_xn[i * 128 + lane];
        float av1 = s_xn[i * 128 + 64 + lane];
        const float4* wp = (const float4*)(s_w1 + i * H + wb);
        float4 wA = wp[0], wB = wp[1];
        acc0[0] = fmaf(av0, wA.x, acc0[0]); acc1[0] = fmaf(av1, wA.x, acc1[0]);
        acc0[1] = fmaf(av0, wA.y, acc0[1]); acc1[1] = fmaf(av1, wA.y, acc1[1]);
        acc0[2] = fmaf(av0, wA.z, acc0[2]); acc1[2] = fmaf(av1, wA.z, acc1[2]);
        acc0[3] = fmaf(av0, wA.w, acc0[3]); acc1[3] = fmaf(av1, wA.w, acc1[3]);
        acc0[4] = fmaf(av0, wB.x, acc0[4]); acc1[4] = fmaf(av1, wB.x, acc1[4]);
        acc0[5] = fmaf(av0, wB.y, acc0[5]); acc1[5] = fmaf(av1, wB.y, acc1[5]);
        acc0[6] = fmaf(av0, wB.z, acc0[6]); acc1[6] = fmaf(av1, wB.z, acc1[6]);
        acc0[7] = fmaf(av0, wB.w, acc0[7]); acc1[7] = fmaf(av1, wB.w, acc1[7]);
    }
    {
        unsigned int h0[4], l0[4], h1[4], l1[4];
#pragma unroll
        for (int q = 0; q < 4; q++) {
            float v0 = fmaxf(acc0[2 * q], 0.0f), v1 = fmaxf(acc0[2 * q + 1], 0.0f);
            unsigned short a = f2bf(v0), b = f2bf(v1);
            h0[q] = (unsigned)a | ((unsigned)b << 16);
            l0[q] = (unsigned)f2bf(v0 - bf2f(a)) | ((unsigned)f2bf(v1 - bf2f(b)) << 16);
            float u0 = fmaxf(acc1[2 * q], 0.0f), u1 = fmaxf(acc1[2 * q + 1], 0.0f);
            unsigned short c = f2bf(u0), d = f2bf(u1);
            h1[q] = (unsigned)c | ((unsigned)d << 16);
            l1[q] = (unsigned)f2bf(u0 - bf2f(c)) | ((unsigned)f2bf(u1 - bf2f(d)) << 16);
        }
        *(uint4*)&s_Ahi[lane * 72 + wb]        = make_uint4(h0[0], h0[1], h0[2], h0[3]);
        *(uint4*)&s_Alo[lane * 72 + wb]        = make_uint4(l0[0], l0[1], l0[2], l0[3]);
        *(uint4*)&s_Ahi[(64 + lane) * 72 + wb] = make_uint4(h1[0], h1[1], h1[2], h1[3]);
        *(uint4*)&s_Alo[(64 + lane) * 72 + wb] = make_uint4(l1[0], l1[1], l1[2], l1[3]);
    }
    __syncthreads();

    int labA = w * 16 + col;
    int labC = w * 16 + kg * 4;
    bf8 Ahi0 = *(const bf8*)&s_Ahi[labA * 72 + kg * 8];
    bf8 Ahi1 = *(const bf8*)&s_Ahi[labA * 72 + 32 + kg * 8];
    bf8 Alo0 = *(const bf8*)&s_Alo[labA * 72 + kg * 8];
    bf8 Alo1 = *(const bf8*)&s_Alo[labA * 72 + 32 + kg * 8];
    int gv[4], mv[4];
#pragma unroll
    for (int r = 0; r < 4; r++) { gv[r] = s_gi[labC + r]; mv[r] = s_mi[labC + r]; }

    f32x4 p1[4];
#pragma unroll
    for (int nt = 0; nt < 4; nt++) {
        int brow = nt * 16 + col;
        bf8 Bhi0 = *(const bf8*)&s_Bhi[brow * 72 + kg * 8];
        bf8 Bhi1 = *(const bf8*)&s_Bhi[brow * 72 + 32 + kg * 8];
        bf8 Blo0 = *(const bf8*)&s_Blo[brow * 72 + kg * 8];
        bf8 Blo1 = *(const bf8*)&s_Blo[brow * 72 + 32 + kg * 8];
        int dim = nt * 16 + col;
        f32x4 c;
#pragma unroll
        for (int r = 0; r < 4; r++)
            c[r] = aggr_contrib[gv[r] * H + dim] + mh_contrib[(long)mv[r] * H + dim];
        c = __builtin_amdgcn_mfma_f32_16x16x32_bf16(Alo0, Bhi0, c, 0, 0, 0);
        c = __builtin_amdgcn_mfma_f32_16x16x32_bf16(Alo1, Bhi1, c, 0, 0, 0);
        c = __builtin_amdgcn_mfma_f32_16x16x32_bf16(Ahi0, Blo0, c, 0, 0, 0);
        c = __builtin_amdgcn_mfma_f32_16x16x32_bf16(Ahi1, Blo1, c, 0, 0, 0);
        c = __builtin_amdgcn_mfma_f32_16x16x32_bf16(Ahi0, Bhi0, c, 0, 0, 0);
        c = __builtin_amdgcn_mfma_f32_16x16x32_bf16(Ahi1, Bhi1, c, 0, 0, 0);
        p1[nt] = c;
    }
    __syncthreads();

#pragma unroll
    for (int nt = 0; nt < 4; nt++) {
#pragma unroll
        for (int r = 0; r < 4; r++) {
            float v = fmaxf(p1[nt][r], 0.0f);
            unsigned short hi = f2bf(v);
            unsigned short lo = f2bf(v - bf2f(hi));
            int lab = labC + r;
            s_Ahi[lab * 72 + nt * 16 + col] = hi;
            s_Alo[lab * 72 + nt * 16 + col] = lo;
        }
    }
#pragma unroll
    for (int s = 0; s < 8; s++) {
        int idx = tid + s * 512;
        int i = idx >> 6, j = idx & 63;
        float v = W2comb[idx];
        unsigned short hi = f2bf(v);
        unsigned short lo = f2bf(v - bf2f(hi));
        s_Bhi[j * 72 + i] = hi;
        s_Blo[j * 72 + i] = lo;
    }
    __syncthreads();

    bf8 Hhi0 = *(const bf8*)&s_Ahi[labA * 72 + kg * 8];
    bf8 Hhi1 = *(const bf8*)&s_Ahi[labA * 72 + 32 + kg * 8];
    bf8 Hlo0 = *(const bf8*)&s_Alo[labA * 72 + kg * 8];
    bf8 Hlo1 = *(const bf8*)&s_Alo[labA * 72 + 32 + kg * 8];

    float sv[4] = {0.0f, 0.0f, 0.0f, 0.0f};
#pragma unroll
    for (int nt = 0; nt < 4; nt++) {
        int brow = nt * 16 + col;
        bf8 Bhi0 = *(const bf8*)&s_Bhi[brow * 72 + kg * 8];
        bf8 Bhi1 = *(const bf8*)&s_Bhi[brow * 72 + 32 + kg * 8];
        bf8 Blo0 = *(const bf8*)&s_Blo[brow * 72 + kg * 8];
        bf8 Blo1 = *(const bf8*)&s_Blo[brow * 72 + 32 + kg * 8];
        int dim = nt * 16 + col;
        float bz = bias2[dim];
        f32x4 c = {bz, bz, bz, bz};
        c = __builtin_amdgcn_mfma_f32_16x16x32_bf16(Hlo0, Bhi0, c, 0, 0, 0);
        c = __builtin_amdgcn_mfma_f32_16x16x32_bf16(Hlo1, Bhi1, c, 0, 0, 0);
        c = __builtin_amdgcn_mfma_f32_16x16x32_bf16(Hhi0, Blo0, c, 0, 0, 0);
        c = __builtin_amdgcn_mfma_f32_16x16x32_bf16(Hhi1, Blo1, c, 0, 0, 0);
        c = __builtin_amdgcn_mfma_f32_16x16x32_bf16(Hhi0, Bhi0, c, 0, 0, 0);
        c = __builtin_amdgcn_mfma_f32_16x16x32_bf16(Hhi1, Bhi1, c, 0, 0, 0);
        float ow = o_w2[dim];
#pragma unroll
        for (int r = 0; r < 4; r++)
            sv[r] = fmaf(fmaxf(c[r], 0.0f), ow, sv[r]);
    }
#pragma unroll
    for (int r = 0; r < 4; r++) {
        sv[r] += __shfl_xor(sv[r], 1);
        sv[r] += __shfl_xor(sv[r], 2);
        sv[r] += __shfl_xor(sv[r], 4);
        sv[r] += __shfl_xor(sv[r], 8);
    }
    if (col == 0) {
        float ob = o_b2[0];
#pragma unroll
        for (int r = 0; r < 4; r++)
            out[blockIdx.x * 128 + labC + r] = ob + sv[r];
    }
}

// ---------------------------------------------------------------------------
extern "C" void kernel_launch(void* const* d_in, const int* in_sizes, int n_in,
                              void* d_out, int out_size, void* d_ws, size_t ws_size,
                              hipStream_t stream)
{
    (void)n_in; (void)out_size; (void)ws_size;
    const float* x_tasks         = (const float*)d_in[0];
    const float* x_machines      = (const float*)d_in[1];
    const int*   x_tasks_batch   = (const int*)d_in[2];
    const int*   x_machines_batch= (const int*)d_in[3];
    const int*   task_label_idx  = (const int*)d_in[4];
    const float* t_ln_g = (const float*)d_in[5];
    const float* t_ln_b = (const float*)d_in[6];
    const float *m_ln_g, *m_ln_b, *t_w1, *t_b1, *t_w2, *t_b2;
    if (in_sizes[7] == DM) {
        m_ln_g = (const float*)d_in[7];  m_ln_b = (const float*)d_in[8];
        t_w1   = (const float*)d_in[9];  t_b1   = (const float*)d_in[10];
        t_w2   = (const float*)d_in[11]; t_b2   = (const float*)d_in[12];
    } else {
        t_w1   = (const float*)d_in[7];  t_b1   = (const float*)d_in[8];
        t_w2   = (const float*)d_in[9];  t_b2   = (const float*)d_in[10];
        m_ln_g = (const float*)d_in[11]; m_ln_b = (const float*)d_in[12];
    }
    const float* m_w1 = (const float*)d_in[13]; const float* m_b1 = (const float*)d_in[14];
    const float* m_w2 = (const float*)d_in[15]; const float* m_b2 = (const float*)d_in[16];
    const float* a_w1 = (const float*)d_in[17]; const float* a_b1 = (const float*)d_in[18];
    const float* a_w2 = (const float*)d_in[19]; const float* a_b2 = (const float*)d_in[20];
    const float* lg_w1= (const float*)d_in[21]; const float* lg_b1= (const float*)d_in[22];
    const float* lg_w2= (const float*)d_in[23]; const float* lg_b2= (const float*)d_in[24];
    const float* o_w1 = (const float*)d_in[25]; const float* o_b1 = (const float*)d_in[26];
    const float* o_w2 = (const float*)d_in[27]; const float* o_b2 = (const float*)d_in[28];

    float* ws = (float*)d_ws;
    float* mh_contrib    = ws;                  // 2049*64 = 131136
    float* mh_arr        = ws + 131136;         // 2048*64 = 131072
    float* t_sum_partial = ws + 262208;         // 512*64  = 32768
    float* t_cnt_partial = ws + 294976;         // 512
    float* W_comb        = ws + 295488;         // 4096
    float* W2comb        = ws + 299584;         // 4096
    float* biasA         = ws + 303680;         // 64
    float* bias2         = ws + 303744;         // 64
    float* aggr_contrib  = ws + 303808;         // 4096
    int*   cum           = (int*)(ws + 307904); // 64

    k_front<<<640, 256, 0, stream>>>(x_tasks, t_ln_g, t_ln_b, t_w1, t_b1,
                                     x_machines, m_ln_g, m_ln_b, m_w1, m_b1, m_w2, m_b2,
                                     lg_w1, t_w2, lg_w2, o_w1, t_b2, lg_b1, lg_b2, o_b1,
                                     t_sum_partial, t_cnt_partial, mh_arr, mh_contrib,
                                     W_comb, W2comb, biasA, bias2);
    k_graph<<<64, 64, 0, stream>>>(t_sum_partial, t_cnt_partial, mh_arr, x_machines_batch,
                                   t_w2, t_b2, a_w1, a_b1, a_w2, a_b2, lg_w1, biasA,
                                   aggr_contrib, cum);
    k_labels_mma<<<512, 512, 0, stream>>>(x_tasks, x_tasks_batch, task_label_idx,
                                          t_ln_g, t_ln_b, t_w1, t_b1, W_comb, W2comb, bias2,
                                          o_w2, o_b2, aggr_contrib, mh_contrib, cum,
                                          (float*)d_out);
}